// Round 5
// baseline (181.924 us; speedup 1.0000x reference)
//
#include <hip/hip_runtime.h>

typedef __attribute__((ext_vector_type(8))) short short8;
typedef __attribute__((ext_vector_type(4))) float f32x4;
typedef __attribute__((ext_vector_type(4))) int i32x4;

// fp32 -> bf16 round-to-nearest-even
__device__ __forceinline__ unsigned short f2bf(float f) {
  unsigned u = __builtin_bit_cast(unsigned, f);
  u += 0x7fffu + ((u >> 16) & 1u);
  return (unsigned short)(u >> 16);
}

// ---------------------------------------------------------------------------
// prep: blocks [0,512):      per-(b,i) stats + exact fp32 copies (out0/out1)
//       blocks [512,1664):   W1..W4 fp32 -> bf16 MFMA B-fragment swizzle
//       blocks [1664,5760):  userb = bf16(user), contiguous vector pass
// ---------------------------------------------------------------------------
__global__ __launch_bounds__(256) void prep(
    const float* __restrict__ user, const float* __restrict__ ris,
    const float* __restrict__ W1, const float* __restrict__ W2,
    const float* __restrict__ W3, const float* __restrict__ W4,
    unsigned short* __restrict__ m1b, unsigned short* __restrict__ m2b,
    int* __restrict__ am, unsigned short* __restrict__ meanb,
    unsigned short* __restrict__ risb, unsigned short* __restrict__ userb,
    unsigned short* __restrict__ W1f, unsigned short* __restrict__ W2f,
    unsigned short* __restrict__ W3f, unsigned short* __restrict__ W4f,
    float* __restrict__ out0, float* __restrict__ out1) {
  if (blockIdx.x < 512) {
    int idx = blockIdx.x * 256 + threadIdx.x;  // 0..131071 (B*IN)
    int b = idx >> 7, i = idx & 127;
    const float* up = user + (size_t)(b * 64) * 128 + i;
    float* op = out0 + (size_t)(b * 64) * 384 + i;
    float s = 0.f, m1 = -3.402823466e38f, m2 = -3.402823466e38f;
    int amx = 0;
    #pragma unroll 8
    for (int k = 0; k < 64; ++k) {
      float u = up[(size_t)k * 128];
      op[(size_t)k * 384] = u;   // exact fp32 copy
      s += u;
      if (u > m1) { m2 = m1; m1 = u; amx = k; }
      else if (u > m2) { m2 = u; }
    }
    m1b[idx] = f2bf(m1);
    m2b[idx] = f2bf(m2);
    am[idx] = amx;
    meanb[idx] = f2bf(s * (1.f / 64.f));
    float rv = ris[idx];
    out1[(size_t)b * 384 + i] = rv;  // exact fp32 copy
    risb[idx] = f2bf(rv);
  } else if (blockIdx.x < 1664) {
    int idx = (blockIdx.x - 512) * 256 + threadIdx.x;  // 0..294911
    const float* src; unsigned short* dst; int kb; int rel;
    if (idx < 98304)        { src = W1; dst = W1f; kb = 12; rel = idx; }
    else if (idx < 163840)  { src = W2; dst = W2f; kb = 8;  rel = idx - 98304; }
    else if (idx < 229376)  { src = W3; dst = W3f; kb = 8;  rel = idx - 163840; }
    else                    { src = W4; dst = W4f; kb = 8;  rel = idx - 229376; }
    int kk = rel >> 8, n = rel & 255;
    int lane = (n & 15) | (((kk >> 3) & 3) << 4);
    int di = (((n >> 4) * kb + (kk >> 5)) * 64 + lane) * 8 + (kk & 7);
    dst[di] = f2bf(src[rel]);
  } else {
    // contiguous bf16 conversion of user: 8 elems per thread
    size_t e = ((size_t)(blockIdx.x - 1664) * 256 + threadIdx.x) * 8;
    f32x4 t0 = *(const f32x4*)(user + e);
    f32x4 t1 = *(const f32x4*)(user + e + 4);
    short8 t;
    #pragma unroll
    for (int j = 0; j < 4; ++j) { t[j] = (short)f2bf(t0[j]); t[4 + j] = (short)f2bf(t1[j]); }
    *(short8*)(userb + e) = t;
  }
}

// ---------------------------------------------------------------------------
// fused 2-layer MLP. Block = 32 rows x 256 cols, 4 waves N-split (32x64 each),
// acc[2][4]. All A-operands bf16 (userb / stats-built loo / risb broadcast).
// Weights from L2-resident swizzled global. H in 16 KiB XOR-swizzled LDS.
// Single __syncthreads per block. 2048 user blocks + 32 RIS blocks.
// ---------------------------------------------------------------------------
template<int MODE>
__device__ __forceinline__ void mlp_body(
    int bx, unsigned short* __restrict__ Hb,
    const unsigned short* __restrict__ userb,
    const unsigned short* __restrict__ m1b, const unsigned short* __restrict__ m2b,
    const int* __restrict__ am,
    const unsigned short* __restrict__ risb, const unsigned short* __restrict__ meanb,
    const unsigned short* __restrict__ Wa, const unsigned short* __restrict__ Wb,
    const float* __restrict__ ba, const float* __restrict__ bb,
    float* __restrict__ out) {
  constexpr int NFS = (MODE == 0) ? 12 : 8;   // K1/32
  const int tid = threadIdx.x;
  const int lane = tid & 63, wn = tid >> 6;   // 4 waves, N-split
  const int row0 = bx * 32;
  const int r = lane & 15;
  const int k8 = (lane >> 4) * 8;
  const int b = row0 >> 6;                    // batch (MODE 0)
  const int kbase = (bx & 1) * 32;            // k-offset of this block in batch

  f32x4 acc[2][4];
  #pragma unroll
  for (int a = 0; a < 2; ++a)
    #pragma unroll
    for (int p = 0; p < 4; ++p) acc[a][p] = (f32x4)0.f;

  // ---- layer 1 ----
  #pragma unroll
  for (int fs = 0; fs < NFS; ++fs) {
    short8 af[2];
    if constexpr (MODE == 0) {
      if (fs < 4) {               // user chunk (bf16 direct)
        #pragma unroll
        for (int mf = 0; mf < 2; ++mf)
          af[mf] = *(const short8*)&userb[(size_t)(row0 + mf * 16 + r) * 128 + fs * 32 + k8];
      } else if (fs < 8) {        // leave-one-out max from stats (L1-hot)
        int c0 = b * 128 + (fs - 4) * 32 + k8;
        short8 m1v = *(const short8*)&m1b[c0];
        short8 m2v = *(const short8*)&m2b[c0];
        i32x4 a0 = *(const i32x4*)&am[c0];
        i32x4 a1 = *(const i32x4*)&am[c0 + 4];
        #pragma unroll
        for (int mf = 0; mf < 2; ++mf) {
          int rr = kbase + mf * 16 + r;       // this row's k within batch
          short8 t;
          #pragma unroll
          for (int j = 0; j < 4; ++j) {
            t[j]     = (a0[j] == rr) ? m2v[j]     : m1v[j];
            t[4 + j] = (a1[j] == rr) ? m2v[4 + j] : m1v[4 + j];
          }
          af[mf] = t;
        }
      } else {                    // RIS broadcast chunk
        short8 v = *(const short8*)&risb[b * 128 + (fs - 8) * 32 + k8];
        af[0] = v; af[1] = v;
      }
    } else {
      const unsigned short* src = (fs < 4) ? risb : meanb;
      #pragma unroll
      for (int mf = 0; mf < 2; ++mf)
        af[mf] = *(const short8*)&src[(size_t)(row0 + mf * 16 + r) * 128 + (fs & 3) * 32 + k8];
    }
    short8 bfr[4];
    #pragma unroll
    for (int nf = 0; nf < 4; ++nf)
      bfr[nf] = *(const short8*)&Wa[(size_t)(((wn * 4 + nf) * NFS + fs) * 64 + lane) * 8];
    #pragma unroll
    for (int mf = 0; mf < 2; ++mf)
      #pragma unroll
      for (int nf = 0; nf < 4; ++nf)
        acc[mf][nf] = __builtin_amdgcn_mfma_f32_16x16x32_bf16(af[mf], bfr[nf], acc[mf][nf], 0, 0, 0);
  }

  // ---- layer-1 epilogue: bias + relu -> H (bf16, XOR-swizzled LDS) ----
  float bav[4];
  #pragma unroll
  for (int nf = 0; nf < 4; ++nf) bav[nf] = ba[wn * 64 + nf * 16 + (lane & 15)];
  #pragma unroll
  for (int mf = 0; mf < 2; ++mf)
    #pragma unroll
    for (int nf = 0; nf < 4; ++nf)
      #pragma unroll
      for (int j = 0; j < 4; ++j) {
        int rr = mf * 16 + ((lane >> 4) * 4) + j;
        int col = wn * 64 + nf * 16 + (lane & 15);
        int c = col >> 3;
        Hb[rr * 256 + ((c ^ (rr & 7)) << 3) + (col & 7)] =
            f2bf(fmaxf(acc[mf][nf][j] + bav[nf], 0.f));
      }
  __syncthreads();

  // ---- layer 2: H(32x256) @ Wb(256x256) ----
  #pragma unroll
  for (int a = 0; a < 2; ++a)
    #pragma unroll
    for (int p = 0; p < 4; ++p) acc[a][p] = (f32x4)0.f;
  #pragma unroll
  for (int kc = 0; kc < 8; ++kc) {
    short8 af[2], bfr[4];
    #pragma unroll
    for (int mf = 0; mf < 2; ++mf) {
      int rr = mf * 16 + (lane & 15);
      int c = kc * 4 + (lane >> 4);
      af[mf] = *(const short8*)(Hb + rr * 256 + ((c ^ (rr & 7)) << 3));
    }
    #pragma unroll
    for (int nf = 0; nf < 4; ++nf)
      bfr[nf] = *(const short8*)&Wb[(size_t)(((wn * 4 + nf) * 8 + kc) * 64 + lane) * 8];
    #pragma unroll
    for (int mf = 0; mf < 2; ++mf)
      #pragma unroll
      for (int nf = 0; nf < 4; ++nf)
        acc[mf][nf] = __builtin_amdgcn_mfma_f32_16x16x32_bf16(af[mf], bfr[nf], acc[mf][nf], 0, 0, 0);
  }

  // ---- layer-2 epilogue: bias, fp32 store to out cols 128..383 ----
  float bbv[4];
  #pragma unroll
  for (int nf = 0; nf < 4; ++nf) bbv[nf] = bb[wn * 64 + nf * 16 + (lane & 15)];
  #pragma unroll
  for (int mf = 0; mf < 2; ++mf)
    #pragma unroll
    for (int nf = 0; nf < 4; ++nf)
      #pragma unroll
      for (int j = 0; j < 4; ++j) {
        int rr = mf * 16 + ((lane >> 4) * 4) + j;
        int col = wn * 64 + nf * 16 + (lane & 15);
        out[(size_t)(row0 + rr) * 384 + 128 + col] = acc[mf][nf][j] + bbv[nf];
      }
}

__global__ __launch_bounds__(256, 8) void fused(
    const unsigned short* __restrict__ userb,
    const unsigned short* __restrict__ m1b, const unsigned short* __restrict__ m2b,
    const int* __restrict__ am,
    const unsigned short* __restrict__ risb, const unsigned short* __restrict__ meanb,
    const unsigned short* __restrict__ W1f, const unsigned short* __restrict__ W2f,
    const unsigned short* __restrict__ W3f, const unsigned short* __restrict__ W4f,
    const float* __restrict__ b1, const float* __restrict__ b2,
    const float* __restrict__ b3, const float* __restrict__ b4,
    float* __restrict__ out0, float* __restrict__ out1) {
  __shared__ unsigned short Hb[32 * 256];   // 16 KiB, XOR-swizzled
  if (blockIdx.x < 2048)
    mlp_body<0>(blockIdx.x, Hb, userb, m1b, m2b, am, risb, meanb,
                W1f, W2f, b1, b2, out0);
  else
    mlp_body<1>(blockIdx.x - 2048, Hb, userb, m1b, m2b, am, risb, meanb,
                W3f, W4f, b3, b4, out1);
}

// ---------------------------------------------------------------------------
extern "C" void kernel_launch(void* const* d_in, const int* in_sizes, int n_in,
                              void* d_out, int out_size, void* d_ws, size_t ws_size,
                              hipStream_t stream) {
  const float* user = (const float*)d_in[0];
  const float* ris  = (const float*)d_in[1];
  const float* W1 = (const float*)d_in[4];
  const float* b1 = (const float*)d_in[5];
  const float* W2 = (const float*)d_in[6];
  const float* b2 = (const float*)d_in[7];
  const float* W3 = (const float*)d_in[8];
  const float* b3 = (const float*)d_in[9];
  const float* W4 = (const float*)d_in[10];
  const float* b4 = (const float*)d_in[11];

  float* out0 = (float*)d_out;                         // (65536, 384)
  float* out1 = out0 + (size_t)65536 * 384;            // (1024, 384)

  char* ws = (char*)d_ws;
  unsigned short* m1b   = (unsigned short*)(ws);            // 131072 bf16
  unsigned short* m2b   = (unsigned short*)(ws + 262144);
  int*            amv   = (int*)(ws + 524288);              // 131072 i32
  unsigned short* meanb = (unsigned short*)(ws + 1048576);
  unsigned short* risb  = (unsigned short*)(ws + 1310720);
  unsigned short* W1f   = (unsigned short*)(ws + 1572864);  // 98304 bf16
  unsigned short* W2f   = (unsigned short*)(ws + 1769472);  // 65536 bf16
  unsigned short* W3f   = (unsigned short*)(ws + 1900544);
  unsigned short* W4f   = (unsigned short*)(ws + 2031616);
  unsigned short* userb = (unsigned short*)(ws + 2162688);  // 8388608 bf16 = 16 MiB

  hipLaunchKernelGGL(prep, dim3(5760), dim3(256), 0, stream,
                     user, ris, W1, W2, W3, W4,
                     m1b, m2b, amv, meanb, risb, userb,
                     W1f, W2f, W3f, W4f, out0, out1);
  hipLaunchKernelGGL(fused, dim3(2080), dim3(256), 0, stream,
                     userb, m1b, m2b, amv, risb, meanb,
                     W1f, W2f, W3f, W4f, b1, b2, b3, b4, out0, out1);
}

// Round 6
// 109.700 us; speedup vs baseline: 1.6584x; 1.6584x over previous
//
#include <hip/hip_runtime.h>

typedef __attribute__((ext_vector_type(8))) short short8;
typedef __attribute__((ext_vector_type(4))) float f32x4;
typedef __attribute__((ext_vector_type(4))) int i32x4;

// fp32 -> bf16 round-to-nearest-even
__device__ __forceinline__ unsigned short f2bf(float f) {
  unsigned u = __builtin_bit_cast(unsigned, f);
  u += 0x7fffu + ((u >> 16) & 1u);
  return (unsigned short)(u >> 16);
}

// ---------------------------------------------------------------------------
// prep: blocks [0,512):      per-(b,i) stats + exact fp32 copies (out0/out1)
//       blocks [512,1664):   W1..W4 fp32 -> bf16 MFMA B-fragment swizzle
//       blocks [1664,5760):  userb = bf16(user), contiguous vector pass
// ---------------------------------------------------------------------------
__global__ __launch_bounds__(256) void prep(
    const float* __restrict__ user, const float* __restrict__ ris,
    const float* __restrict__ W1, const float* __restrict__ W2,
    const float* __restrict__ W3, const float* __restrict__ W4,
    unsigned short* __restrict__ m1b, unsigned short* __restrict__ m2b,
    int* __restrict__ am, unsigned short* __restrict__ meanb,
    unsigned short* __restrict__ risb, unsigned short* __restrict__ userb,
    unsigned short* __restrict__ W1f, unsigned short* __restrict__ W2f,
    unsigned short* __restrict__ W3f, unsigned short* __restrict__ W4f,
    float* __restrict__ out0, float* __restrict__ out1) {
  if (blockIdx.x < 512) {
    int idx = blockIdx.x * 256 + threadIdx.x;  // 0..131071 (B*IN)
    int b = idx >> 7, i = idx & 127;
    const float* up = user + (size_t)(b * 64) * 128 + i;
    float* op = out0 + (size_t)(b * 64) * 384 + i;
    float s = 0.f, m1 = -3.402823466e38f, m2 = -3.402823466e38f;
    int amx = 0;
    #pragma unroll 8
    for (int k = 0; k < 64; ++k) {
      float u = up[(size_t)k * 128];
      op[(size_t)k * 384] = u;   // exact fp32 copy
      s += u;
      if (u > m1) { m2 = m1; m1 = u; amx = k; }
      else if (u > m2) { m2 = u; }
    }
    m1b[idx] = f2bf(m1);
    m2b[idx] = f2bf(m2);
    am[idx] = amx;
    meanb[idx] = f2bf(s * (1.f / 64.f));
    float rv = ris[idx];
    out1[(size_t)b * 384 + i] = rv;  // exact fp32 copy
    risb[idx] = f2bf(rv);
  } else if (blockIdx.x < 1664) {
    int idx = (blockIdx.x - 512) * 256 + threadIdx.x;  // 0..294911
    const float* src; unsigned short* dst; int kb; int rel;
    if (idx < 98304)        { src = W1; dst = W1f; kb = 12; rel = idx; }
    else if (idx < 163840)  { src = W2; dst = W2f; kb = 8;  rel = idx - 98304; }
    else if (idx < 229376)  { src = W3; dst = W3f; kb = 8;  rel = idx - 163840; }
    else                    { src = W4; dst = W4f; kb = 8;  rel = idx - 229376; }
    int kk = rel >> 8, n = rel & 255;
    int lane = (n & 15) | (((kk >> 3) & 3) << 4);
    int di = (((n >> 4) * kb + (kk >> 5)) * 64 + lane) * 8 + (kk & 7);
    dst[di] = f2bf(src[rel]);
  } else {
    // contiguous bf16 conversion of user: 8 elems per thread
    size_t e = ((size_t)(blockIdx.x - 1664) * 256 + threadIdx.x) * 8;
    f32x4 t0 = *(const f32x4*)(user + e);
    f32x4 t1 = *(const f32x4*)(user + e + 4);
    short8 t;
    #pragma unroll
    for (int j = 0; j < 4; ++j) { t[j] = (short)f2bf(t0[j]); t[4 + j] = (short)f2bf(t1[j]); }
    *(short8*)(userb + e) = t;
  }
}

// ---------------------------------------------------------------------------
// persist: 256 blocks x 512 thr (8 waves, N-split 32 cols/wave).
// Weights live in REGISTERS for the whole kernel (loaded once):
//   wA = W1 slice (24 frags, 96 VGPR), wB = W2 slice (16 frags, 64 VGPR).
// Each block processes 4 row-tiles of 64 rows (= 4 batches).
// Per iter: L1 MFMA burst (reg weights, streamed bf16 A) -> H in LDS ->
// L2 MFMA burst (reg weights, ds_read A) -> fp32 stores. 2 barriers/iter.
// Blocks 0..15 run one extra RIS tile with W3/W4 reloaded into wA/wB.
// ---------------------------------------------------------------------------
__global__ __launch_bounds__(512, 2) void persist(
    const unsigned short* __restrict__ userb,
    const unsigned short* __restrict__ m1b, const unsigned short* __restrict__ m2b,
    const int* __restrict__ am,
    const unsigned short* __restrict__ risb, const unsigned short* __restrict__ meanb,
    const unsigned short* __restrict__ W1f, const unsigned short* __restrict__ W2f,
    const unsigned short* __restrict__ W3f, const unsigned short* __restrict__ W4f,
    const float* __restrict__ b1, const float* __restrict__ b2,
    const float* __restrict__ b3, const float* __restrict__ b4,
    float* __restrict__ out0, float* __restrict__ out1) {
  __shared__ unsigned short Hb[64 * 256];   // 32 KiB, XOR-swizzled

  const int tid = threadIdx.x;
  const int lane = tid & 63, wn = tid >> 6;   // 8 waves, 32-col slices
  const int r = lane & 15;
  const int k8 = (lane >> 4) * 8;
  const int j4 = (lane >> 4) * 4;

  // ---- persistent weight registers (user path) ----
  short8 wA[24], wB[16];
  #pragma unroll
  for (int nf = 0; nf < 2; ++nf)
    #pragma unroll
    for (int fs = 0; fs < 12; ++fs)
      wA[nf * 12 + fs] = *(const short8*)&W1f[(size_t)(((wn * 2 + nf) * 12 + fs) * 64 + lane) * 8];
  #pragma unroll
  for (int nf = 0; nf < 2; ++nf)
    #pragma unroll
    for (int kc = 0; kc < 8; ++kc)
      wB[nf * 8 + kc] = *(const short8*)&W2f[(size_t)(((wn * 2 + nf) * 8 + kc) * 64 + lane) * 8];

  float ba[2] = { b1[wn * 32 + r], b1[wn * 32 + 16 + r] };
  float bb[2] = { b2[wn * 32 + r], b2[wn * 32 + 16 + r] };

  for (int it = 0; it < 4; ++it) {
    const int b = blockIdx.x * 4 + it;   // batch index; tile rows = batch's 64 k's
    const int row0 = b * 64;

    // ---- layer 1: 96 MFMA from register weights ----
    f32x4 acc[4][2];
    #pragma unroll
    for (int a = 0; a < 4; ++a) { acc[a][0] = (f32x4)0.f; acc[a][1] = (f32x4)0.f; }

    #pragma unroll
    for (int fs = 0; fs < 4; ++fs) {           // user chunk (bf16 direct)
      short8 af[4];
      #pragma unroll
      for (int mf = 0; mf < 4; ++mf)
        af[mf] = *(const short8*)&userb[(size_t)(row0 + mf * 16 + r) * 128 + fs * 32 + k8];
      #pragma unroll
      for (int mf = 0; mf < 4; ++mf)
        #pragma unroll
        for (int nf = 0; nf < 2; ++nf)
          acc[mf][nf] = __builtin_amdgcn_mfma_f32_16x16x32_bf16(af[mf], wA[nf * 12 + fs], acc[mf][nf], 0, 0, 0);
    }
    #pragma unroll
    for (int fs = 0; fs < 4; ++fs) {           // leave-one-out max chunk
      int c0 = b * 128 + fs * 32 + k8;
      short8 m1v = *(const short8*)&m1b[c0];
      short8 m2v = *(const short8*)&m2b[c0];
      i32x4 a0 = *(const i32x4*)&am[c0];
      i32x4 a1 = *(const i32x4*)&am[c0 + 4];
      #pragma unroll
      for (int mf = 0; mf < 4; ++mf) {
        int rr = mf * 16 + r;                  // this row's k within the batch
        short8 t;
        #pragma unroll
        for (int j = 0; j < 4; ++j) {
          t[j]     = (a0[j] == rr) ? m2v[j]     : m1v[j];
          t[4 + j] = (a1[j] == rr) ? m2v[4 + j] : m1v[4 + j];
        }
        #pragma unroll
        for (int nf = 0; nf < 2; ++nf)
          acc[mf][nf] = __builtin_amdgcn_mfma_f32_16x16x32_bf16(t, wA[nf * 12 + 4 + fs], acc[mf][nf], 0, 0, 0);
      }
    }
    #pragma unroll
    for (int fs = 0; fs < 4; ++fs) {           // RIS broadcast chunk
      short8 v = *(const short8*)&risb[b * 128 + fs * 32 + k8];
      #pragma unroll
      for (int mf = 0; mf < 4; ++mf)
        #pragma unroll
        for (int nf = 0; nf < 2; ++nf)
          acc[mf][nf] = __builtin_amdgcn_mfma_f32_16x16x32_bf16(v, wA[nf * 12 + 8 + fs], acc[mf][nf], 0, 0, 0);
    }

    // ---- H: bias + relu -> XOR-swizzled LDS ----
    #pragma unroll
    for (int mf = 0; mf < 4; ++mf)
      #pragma unroll
      for (int nf = 0; nf < 2; ++nf)
        #pragma unroll
        for (int j = 0; j < 4; ++j) {
          int rr = mf * 16 + j4 + j;
          int col = wn * 32 + nf * 16 + r;
          int c = col >> 3;
          Hb[rr * 256 + ((c ^ (rr & 7)) << 3) + (col & 7)] =
              f2bf(fmaxf(acc[mf][nf][j] + ba[nf], 0.f));
        }
    __syncthreads();

    // ---- layer 2: 64 MFMA from register weights, A from LDS ----
    f32x4 acc2[4][2];
    #pragma unroll
    for (int a = 0; a < 4; ++a) { acc2[a][0] = (f32x4)0.f; acc2[a][1] = (f32x4)0.f; }
    #pragma unroll
    for (int kc = 0; kc < 8; ++kc) {
      short8 af[4];
      #pragma unroll
      for (int mf = 0; mf < 4; ++mf) {
        int rr = mf * 16 + r;
        int c = kc * 4 + (lane >> 4);
        af[mf] = *(const short8*)(Hb + rr * 256 + ((c ^ (rr & 7)) << 3));
      }
      #pragma unroll
      for (int mf = 0; mf < 4; ++mf)
        #pragma unroll
        for (int nf = 0; nf < 2; ++nf)
          acc2[mf][nf] = __builtin_amdgcn_mfma_f32_16x16x32_bf16(af[mf], wB[nf * 8 + kc], acc2[mf][nf], 0, 0, 0);
    }

    // ---- store out0 cols 128..383 (fp32 + bias) ----
    #pragma unroll
    for (int mf = 0; mf < 4; ++mf)
      #pragma unroll
      for (int nf = 0; nf < 2; ++nf)
        #pragma unroll
        for (int j = 0; j < 4; ++j) {
          int rr = mf * 16 + j4 + j;
          int col = wn * 32 + nf * 16 + r;
          out0[(size_t)(row0 + rr) * 384 + 128 + col] = acc2[mf][nf][j] + bb[nf];
        }
    __syncthreads();   // Hb reuse next iter
  }

  // ---- RIS tile (blocks 0..15): reload weights, one extra iter ----
  if (blockIdx.x < 16) {
    #pragma unroll
    for (int nf = 0; nf < 2; ++nf)
      #pragma unroll
      for (int fs = 0; fs < 8; ++fs)
        wA[nf * 12 + fs] = *(const short8*)&W3f[(size_t)(((wn * 2 + nf) * 8 + fs) * 64 + lane) * 8];
    #pragma unroll
    for (int nf = 0; nf < 2; ++nf)
      #pragma unroll
      for (int kc = 0; kc < 8; ++kc)
        wB[nf * 8 + kc] = *(const short8*)&W4f[(size_t)(((wn * 2 + nf) * 8 + kc) * 64 + lane) * 8];
    float ba3[2] = { b3[wn * 32 + r], b3[wn * 32 + 16 + r] };
    float bb4[2] = { b4[wn * 32 + r], b4[wn * 32 + 16 + r] };
    const int row0 = blockIdx.x * 64;

    f32x4 acc[4][2];
    #pragma unroll
    for (int a = 0; a < 4; ++a) { acc[a][0] = (f32x4)0.f; acc[a][1] = (f32x4)0.f; }
    #pragma unroll
    for (int fs = 0; fs < 8; ++fs) {
      const unsigned short* src = (fs < 4) ? risb : meanb;
      short8 af[4];
      #pragma unroll
      for (int mf = 0; mf < 4; ++mf)
        af[mf] = *(const short8*)&src[(size_t)(row0 + mf * 16 + r) * 128 + (fs & 3) * 32 + k8];
      #pragma unroll
      for (int mf = 0; mf < 4; ++mf)
        #pragma unroll
        for (int nf = 0; nf < 2; ++nf)
          acc[mf][nf] = __builtin_amdgcn_mfma_f32_16x16x32_bf16(af[mf], wA[nf * 12 + fs], acc[mf][nf], 0, 0, 0);
    }
    #pragma unroll
    for (int mf = 0; mf < 4; ++mf)
      #pragma unroll
      for (int nf = 0; nf < 2; ++nf)
        #pragma unroll
        for (int j = 0; j < 4; ++j) {
          int rr = mf * 16 + j4 + j;
          int col = wn * 32 + nf * 16 + r;
          int c = col >> 3;
          Hb[rr * 256 + ((c ^ (rr & 7)) << 3) + (col & 7)] =
              f2bf(fmaxf(acc[mf][nf][j] + ba3[nf], 0.f));
        }
    __syncthreads();
    f32x4 acc2[4][2];
    #pragma unroll
    for (int a = 0; a < 4; ++a) { acc2[a][0] = (f32x4)0.f; acc2[a][1] = (f32x4)0.f; }
    #pragma unroll
    for (int kc = 0; kc < 8; ++kc) {
      short8 af[4];
      #pragma unroll
      for (int mf = 0; mf < 4; ++mf) {
        int rr = mf * 16 + r;
        int c = kc * 4 + (lane >> 4);
        af[mf] = *(const short8*)(Hb + rr * 256 + ((c ^ (rr & 7)) << 3));
      }
      #pragma unroll
      for (int mf = 0; mf < 4; ++mf)
        #pragma unroll
        for (int nf = 0; nf < 2; ++nf)
          acc2[mf][nf] = __builtin_amdgcn_mfma_f32_16x16x32_bf16(af[mf], wB[nf * 8 + kc], acc2[mf][nf], 0, 0, 0);
    }
    #pragma unroll
    for (int mf = 0; mf < 4; ++mf)
      #pragma unroll
      for (int nf = 0; nf < 2; ++nf)
        #pragma unroll
        for (int j = 0; j < 4; ++j) {
          int rr = mf * 16 + j4 + j;
          int col = wn * 32 + nf * 16 + r;
          out1[(size_t)(row0 + rr) * 384 + 128 + col] = acc2[mf][nf][j] + bb4[nf];
        }
  }
}

// ---------------------------------------------------------------------------
extern "C" void kernel_launch(void* const* d_in, const int* in_sizes, int n_in,
                              void* d_out, int out_size, void* d_ws, size_t ws_size,
                              hipStream_t stream) {
  const float* user = (const float*)d_in[0];
  const float* ris  = (const float*)d_in[1];
  const float* W1 = (const float*)d_in[4];
  const float* b1 = (const float*)d_in[5];
  const float* W2 = (const float*)d_in[6];
  const float* b2 = (const float*)d_in[7];
  const float* W3 = (const float*)d_in[8];
  const float* b3 = (const float*)d_in[9];
  const float* W4 = (const float*)d_in[10];
  const float* b4 = (const float*)d_in[11];

  float* out0 = (float*)d_out;                         // (65536, 384)
  float* out1 = out0 + (size_t)65536 * 384;            // (1024, 384)

  char* ws = (char*)d_ws;
  unsigned short* m1b   = (unsigned short*)(ws);            // 131072 bf16
  unsigned short* m2b   = (unsigned short*)(ws + 262144);
  int*            amv   = (int*)(ws + 524288);              // 131072 i32
  unsigned short* meanb = (unsigned short*)(ws + 1048576);
  unsigned short* risb  = (unsigned short*)(ws + 1310720);
  unsigned short* W1f   = (unsigned short*)(ws + 1572864);  // 98304 bf16
  unsigned short* W2f   = (unsigned short*)(ws + 1769472);  // 65536 bf16
  unsigned short* W3f   = (unsigned short*)(ws + 1900544);
  unsigned short* W4f   = (unsigned short*)(ws + 2031616);
  unsigned short* userb = (unsigned short*)(ws + 2162688);  // 8388608 bf16 = 16 MiB

  hipLaunchKernelGGL(prep, dim3(5760), dim3(256), 0, stream,
                     user, ris, W1, W2, W3, W4,
                     m1b, m2b, amv, meanb, risb, userb,
                     W1f, W2f, W3f, W4f, out0, out1);
  hipLaunchKernelGGL(persist, dim3(256), dim3(512), 0, stream,
                     userb, m1b, m2b, amv, risb, meanb,
                     W1f, W2f, W3f, W4f, b1, b2, b3, b4, out0, out1);
}

// Round 7
// 64.772 us; speedup vs baseline: 2.8087x; 1.6936x over previous
//
#include <hip/hip_runtime.h>

typedef __attribute__((ext_vector_type(8))) short short8;
typedef __attribute__((ext_vector_type(4))) float f32x4;
typedef __attribute__((ext_vector_type(2))) unsigned u32x2;

// fp32 -> bf16 round-to-nearest-even
__device__ __forceinline__ unsigned short f2bf(float f) {
  unsigned u = __builtin_bit_cast(unsigned, f);
  u += 0x7fffu + ((u >> 16) & 1u);
  return (unsigned short)(u >> 16);
}
__device__ __forceinline__ float bf2f(unsigned short u) {
  return __builtin_bit_cast(float, (unsigned)u << 16);
}

// ---------------------------------------------------------------------------
// wprep: W1..W4 fp32 -> bf16, MFMA B-fragment swizzle. 288 blocks x 256 thr,
// 4 consecutive elements per thread.
// ---------------------------------------------------------------------------
__global__ __launch_bounds__(256) void wprep(
    const float* __restrict__ W1, const float* __restrict__ W2,
    const float* __restrict__ W3, const float* __restrict__ W4,
    unsigned short* __restrict__ W1f, unsigned short* __restrict__ W2f,
    unsigned short* __restrict__ W3f, unsigned short* __restrict__ W4f) {
  int idx = (blockIdx.x * 256 + threadIdx.x) * 4;  // 0..294908
  const float* src; unsigned short* dst; int kb; int rel;
  if (idx < 98304)        { src = W1; dst = W1f; kb = 12; rel = idx; }
  else if (idx < 163840)  { src = W2; dst = W2f; kb = 8;  rel = idx - 98304; }
  else if (idx < 229376)  { src = W3; dst = W3f; kb = 8;  rel = idx - 163840; }
  else                    { src = W4; dst = W4f; kb = 8;  rel = idx - 229376; }
  int kk = rel >> 8, n0 = rel & 255;
  f32x4 t = *(const f32x4*)(src + rel);
  #pragma unroll
  for (int j = 0; j < 4; ++j) {
    int n = n0 + j;
    int lane = (n & 15) | (((kk >> 3) & 3) << 4);
    int di = (((n >> 4) * kb + (kk >> 5)) * 64 + lane) * 8 + (kk & 7);
    dst[di] = f2bf(t[j]);
  }
}

// ---------------------------------------------------------------------------
// fusedU: one batch (64 rows) per block, 512 thr (8 waves, N-split 32 cols).
// Phases: stage user tile->LDS(+out0 fp32 copy) | in-block stats | L1 MFMA
// (A from LDS, loo from stats, ris broadcast) | H->LDS | L2 MFMA | store.
// Writes meanb for the RIS kernel.
// ---------------------------------------------------------------------------
__global__ __launch_bounds__(512, 4) void fusedU(
    const float* __restrict__ user, const float* __restrict__ ris,
    const unsigned short* __restrict__ W1f, const unsigned short* __restrict__ W2f,
    const float* __restrict__ b1, const float* __restrict__ b2,
    float* __restrict__ out0, unsigned short* __restrict__ meanb) {
  __shared__ unsigned short U[64 * 128];    // 16 KiB bf16 user tile, XOR-swizzled
  __shared__ unsigned short Hb[64 * 256];   // 32 KiB H, XOR-swizzled
  __shared__ unsigned short m1s[128], m2s[128], ams[128], risl[128];
  __shared__ float pm1[4][128], pm2[4][128], psum[4][128];
  __shared__ unsigned short pam[4][128];

  const int tid = threadIdx.x;
  const int bx = blockIdx.x;                 // batch index
  const size_t ubase = (size_t)bx * 8192;    // 64*128

  // ---- stage: user tile -> out0 (exact fp32) + U (bf16, swizzled) ----
  #pragma unroll
  for (int it = 0; it < 4; ++it) {
    int e = it * 2048 + tid * 4;             // float idx in tile
    f32x4 t = *(const f32x4*)(user + ubase + e);
    int row = e >> 7, col = e & 127;
    *(f32x4*)(out0 + (size_t)(bx * 64 + row) * 384 + col) = t;
    unsigned p0 = (unsigned)f2bf(t[0]) | ((unsigned)f2bf(t[1]) << 16);
    unsigned p1 = (unsigned)f2bf(t[2]) | ((unsigned)f2bf(t[3]) << 16);
    int cc = col >> 3, sub = col & 7;        // sub in {0,4}
    u32x2 p = {p0, p1};
    *(u32x2*)(U + row * 128 + ((cc ^ (row & 7)) << 3) + sub) = p;
  }
  if (tid < 128) risl[tid] = f2bf(ris[bx * 128 + tid]);
  __syncthreads();

  // ---- stats: per-column mean/max1/max2/argmax over 64 rows ----
  {
    int c = tid & 127, g = tid >> 7;         // 4 row-groups of 16
    int cc = c >> 3, sub = c & 7;
    float m1 = -3.402823466e38f, m2 = -3.402823466e38f, s = 0.f;
    int amx = 0;
    #pragma unroll
    for (int q = 0; q < 16; ++q) {
      int row = g * 16 + q;
      float v = bf2f(U[row * 128 + ((cc ^ (row & 7)) << 3) + sub]);
      s += v;
      if (v > m1) { m2 = m1; m1 = v; amx = row; }
      else if (v > m2) { m2 = v; }
    }
    pm1[g][c] = m1; pm2[g][c] = m2; psum[g][c] = s;
    pam[g][c] = (unsigned short)amx;
  }
  __syncthreads();
  if (tid < 128) {
    int c = tid;
    float m1 = -3.402823466e38f, m2 = -3.402823466e38f, s = 0.f;
    int amx = 0;
    #pragma unroll
    for (int g = 0; g < 4; ++g) {
      float a = pm1[g][c], b = pm2[g][c];
      s += psum[g][c];
      if (a >= m1) { m2 = fmaxf(m1, b); m1 = a; amx = pam[g][c]; }
      else { m2 = fmaxf(m2, a); }
    }
    m1s[c] = f2bf(m1); m2s[c] = f2bf(m2); ams[c] = (unsigned short)amx;
    meanb[bx * 128 + c] = f2bf(s * (1.f / 64.f));
  }
  __syncthreads();

  const int lane = tid & 63, wn = tid >> 6;  // 8 waves, 32-col slices
  const int r = lane & 15;
  const int k8 = (lane >> 4) * 8;
  const int j4 = (lane >> 4) * 4;

  // ---- layer 1: 96 MFMA/wave ----
  f32x4 acc[4][2];
  #pragma unroll
  for (int a = 0; a < 4; ++a) { acc[a][0] = (f32x4)0.f; acc[a][1] = (f32x4)0.f; }

  #pragma unroll
  for (int fs = 0; fs < 4; ++fs) {           // user chunk (LDS)
    short8 af[4];
    #pragma unroll
    for (int mf = 0; mf < 4; ++mf) {
      int row = mf * 16 + r;
      int cc = fs * 4 + (lane >> 4);
      af[mf] = *(const short8*)(U + row * 128 + ((cc ^ (row & 7)) << 3));
    }
    short8 w0 = *(const short8*)&W1f[(size_t)(((wn * 2 + 0) * 12 + fs) * 64 + lane) * 8];
    short8 w1 = *(const short8*)&W1f[(size_t)(((wn * 2 + 1) * 12 + fs) * 64 + lane) * 8];
    #pragma unroll
    for (int mf = 0; mf < 4; ++mf) {
      acc[mf][0] = __builtin_amdgcn_mfma_f32_16x16x32_bf16(af[mf], w0, acc[mf][0], 0, 0, 0);
      acc[mf][1] = __builtin_amdgcn_mfma_f32_16x16x32_bf16(af[mf], w1, acc[mf][1], 0, 0, 0);
    }
  }
  #pragma unroll
  for (int fs = 0; fs < 4; ++fs) {           // leave-one-out chunk (stats)
    int c0 = fs * 32 + k8;
    short8 m1v = *(const short8*)(m1s + c0);
    short8 m2v = *(const short8*)(m2s + c0);
    short8 amv = *(const short8*)(ams + c0);
    short8 w0 = *(const short8*)&W1f[(size_t)(((wn * 2 + 0) * 12 + 4 + fs) * 64 + lane) * 8];
    short8 w1 = *(const short8*)&W1f[(size_t)(((wn * 2 + 1) * 12 + 4 + fs) * 64 + lane) * 8];
    #pragma unroll
    for (int mf = 0; mf < 4; ++mf) {
      int rr = mf * 16 + r;
      short8 t;
      #pragma unroll
      for (int j = 0; j < 8; ++j)
        t[j] = ((unsigned short)amv[j] == (unsigned short)rr) ? m2v[j] : m1v[j];
      acc[mf][0] = __builtin_amdgcn_mfma_f32_16x16x32_bf16(t, w0, acc[mf][0], 0, 0, 0);
      acc[mf][1] = __builtin_amdgcn_mfma_f32_16x16x32_bf16(t, w1, acc[mf][1], 0, 0, 0);
    }
  }
  #pragma unroll
  for (int fs = 0; fs < 4; ++fs) {           // RIS broadcast chunk
    short8 v = *(const short8*)(risl + fs * 32 + k8);
    short8 w0 = *(const short8*)&W1f[(size_t)(((wn * 2 + 0) * 12 + 8 + fs) * 64 + lane) * 8];
    short8 w1 = *(const short8*)&W1f[(size_t)(((wn * 2 + 1) * 12 + 8 + fs) * 64 + lane) * 8];
    #pragma unroll
    for (int mf = 0; mf < 4; ++mf) {
      acc[mf][0] = __builtin_amdgcn_mfma_f32_16x16x32_bf16(v, w0, acc[mf][0], 0, 0, 0);
      acc[mf][1] = __builtin_amdgcn_mfma_f32_16x16x32_bf16(v, w1, acc[mf][1], 0, 0, 0);
    }
  }

  // ---- H: bias + relu -> LDS (swizzled) ----
  float ba[2] = { b1[wn * 32 + r], b1[wn * 32 + 16 + r] };
  #pragma unroll
  for (int mf = 0; mf < 4; ++mf)
    #pragma unroll
    for (int nf = 0; nf < 2; ++nf)
      #pragma unroll
      for (int j = 0; j < 4; ++j) {
        int rr = mf * 16 + j4 + j;
        int col = wn * 32 + nf * 16 + r;
        int cc = col >> 3;
        Hb[rr * 256 + ((cc ^ (rr & 7)) << 3) + (col & 7)] =
            f2bf(fmaxf(acc[mf][nf][j] + ba[nf], 0.f));
      }
  __syncthreads();

  // ---- layer 2: 64 MFMA/wave ----
  f32x4 acc2[4][2];
  #pragma unroll
  for (int a = 0; a < 4; ++a) { acc2[a][0] = (f32x4)0.f; acc2[a][1] = (f32x4)0.f; }
  #pragma unroll
  for (int kc = 0; kc < 8; ++kc) {
    short8 af[4];
    #pragma unroll
    for (int mf = 0; mf < 4; ++mf) {
      int rr = mf * 16 + r;
      int cc = kc * 4 + (lane >> 4);
      af[mf] = *(const short8*)(Hb + rr * 256 + ((cc ^ (rr & 7)) << 3));
    }
    short8 w0 = *(const short8*)&W2f[(size_t)(((wn * 2 + 0) * 8 + kc) * 64 + lane) * 8];
    short8 w1 = *(const short8*)&W2f[(size_t)(((wn * 2 + 1) * 8 + kc) * 64 + lane) * 8];
    #pragma unroll
    for (int mf = 0; mf < 4; ++mf) {
      acc2[mf][0] = __builtin_amdgcn_mfma_f32_16x16x32_bf16(af[mf], w0, acc2[mf][0], 0, 0, 0);
      acc2[mf][1] = __builtin_amdgcn_mfma_f32_16x16x32_bf16(af[mf], w1, acc2[mf][1], 0, 0, 0);
    }
  }

  // ---- store out0 cols 128..383 ----
  float bb[2] = { b2[wn * 32 + r], b2[wn * 32 + 16 + r] };
  #pragma unroll
  for (int mf = 0; mf < 4; ++mf)
    #pragma unroll
    for (int nf = 0; nf < 2; ++nf)
      #pragma unroll
      for (int j = 0; j < 4; ++j) {
        int rr = mf * 16 + j4 + j;
        int col = wn * 32 + nf * 16 + r;
        out0[(size_t)(bx * 64 + rr) * 384 + 128 + col] = acc2[mf][nf][j] + bb[nf];
      }
}

// ---------------------------------------------------------------------------
// fusedR: RIS path. 16 blocks x 512 thr, 64 batches per block.
// A = [ris (fp32->bf16 in-reg) | meanb]; also writes out1 cols 0..127 fp32.
// ---------------------------------------------------------------------------
__global__ __launch_bounds__(512, 4) void fusedR(
    const float* __restrict__ ris, const unsigned short* __restrict__ meanb,
    const unsigned short* __restrict__ W3f, const unsigned short* __restrict__ W4f,
    const float* __restrict__ b3, const float* __restrict__ b4,
    float* __restrict__ out1) {
  __shared__ unsigned short Hb[64 * 256];   // 32 KiB, XOR-swizzled

  const int tid = threadIdx.x;
  const int row0 = blockIdx.x * 64;

  // exact fp32 copy: out1 cols 0..127
  #pragma unroll
  for (int it = 0; it < 4; ++it) {
    int e = it * 2048 + tid * 4;
    f32x4 t = *(const f32x4*)(ris + (size_t)row0 * 128 + e);
    int row = e >> 7, col = e & 127;
    *(f32x4*)(out1 + (size_t)(row0 + row) * 384 + col) = t;
  }

  const int lane = tid & 63, wn = tid >> 6;
  const int r = lane & 15;
  const int k8 = (lane >> 4) * 8;
  const int j4 = (lane >> 4) * 4;

  f32x4 acc[4][2];
  #pragma unroll
  for (int a = 0; a < 4; ++a) { acc[a][0] = (f32x4)0.f; acc[a][1] = (f32x4)0.f; }

  #pragma unroll
  for (int fs = 0; fs < 8; ++fs) {
    short8 af[4];
    if (fs < 4) {
      #pragma unroll
      for (int mf = 0; mf < 4; ++mf) {
        const float* p = &ris[(size_t)(row0 + mf * 16 + r) * 128 + fs * 32 + k8];
        f32x4 t0 = *(const f32x4*)p;
        f32x4 t1 = *(const f32x4*)(p + 4);
        short8 t;
        #pragma unroll
        for (int j = 0; j < 4; ++j) { t[j] = (short)f2bf(t0[j]); t[4 + j] = (short)f2bf(t1[j]); }
        af[mf] = t;
      }
    } else {
      #pragma unroll
      for (int mf = 0; mf < 4; ++mf)
        af[mf] = *(const short8*)&meanb[(size_t)(row0 + mf * 16 + r) * 128 + (fs - 4) * 32 + k8];
    }
    short8 w0 = *(const short8*)&W3f[(size_t)(((wn * 2 + 0) * 8 + fs) * 64 + lane) * 8];
    short8 w1 = *(const short8*)&W3f[(size_t)(((wn * 2 + 1) * 8 + fs) * 64 + lane) * 8];
    #pragma unroll
    for (int mf = 0; mf < 4; ++mf) {
      acc[mf][0] = __builtin_amdgcn_mfma_f32_16x16x32_bf16(af[mf], w0, acc[mf][0], 0, 0, 0);
      acc[mf][1] = __builtin_amdgcn_mfma_f32_16x16x32_bf16(af[mf], w1, acc[mf][1], 0, 0, 0);
    }
  }

  float ba[2] = { b3[wn * 32 + r], b3[wn * 32 + 16 + r] };
  #pragma unroll
  for (int mf = 0; mf < 4; ++mf)
    #pragma unroll
    for (int nf = 0; nf < 2; ++nf)
      #pragma unroll
      for (int j = 0; j < 4; ++j) {
        int rr = mf * 16 + j4 + j;
        int col = wn * 32 + nf * 16 + r;
        int cc = col >> 3;
        Hb[rr * 256 + ((cc ^ (rr & 7)) << 3) + (col & 7)] =
            f2bf(fmaxf(acc[mf][nf][j] + ba[nf], 0.f));
      }
  __syncthreads();

  f32x4 acc2[4][2];
  #pragma unroll
  for (int a = 0; a < 4; ++a) { acc2[a][0] = (f32x4)0.f; acc2[a][1] = (f32x4)0.f; }
  #pragma unroll
  for (int kc = 0; kc < 8; ++kc) {
    short8 af[4];
    #pragma unroll
    for (int mf = 0; mf < 4; ++mf) {
      int rr = mf * 16 + r;
      int cc = kc * 4 + (lane >> 4);
      af[mf] = *(const short8*)(Hb + rr * 256 + ((cc ^ (rr & 7)) << 3));
    }
    short8 w0 = *(const short8*)&W4f[(size_t)(((wn * 2 + 0) * 8 + kc) * 64 + lane) * 8];
    short8 w1 = *(const short8*)&W4f[(size_t)(((wn * 2 + 1) * 8 + kc) * 64 + lane) * 8];
    #pragma unroll
    for (int mf = 0; mf < 4; ++mf) {
      acc2[mf][0] = __builtin_amdgcn_mfma_f32_16x16x32_bf16(af[mf], w0, acc2[mf][0], 0, 0, 0);
      acc2[mf][1] = __builtin_amdgcn_mfma_f32_16x16x32_bf16(af[mf], w1, acc2[mf][1], 0, 0, 0);
    }
  }

  float bb[2] = { b4[wn * 32 + r], b4[wn * 32 + 16 + r] };
  #pragma unroll
  for (int mf = 0; mf < 4; ++mf)
    #pragma unroll
    for (int nf = 0; nf < 2; ++nf)
      #pragma unroll
      for (int j = 0; j < 4; ++j) {
        int rr = mf * 16 + j4 + j;
        int col = wn * 32 + nf * 16 + r;
        out1[(size_t)(row0 + rr) * 384 + 128 + col] = acc2[mf][nf][j] + bb[nf];
      }
}

// ---------------------------------------------------------------------------
extern "C" void kernel_launch(void* const* d_in, const int* in_sizes, int n_in,
                              void* d_out, int out_size, void* d_ws, size_t ws_size,
                              hipStream_t stream) {
  const float* user = (const float*)d_in[0];
  const float* ris  = (const float*)d_in[1];
  const float* W1 = (const float*)d_in[4];
  const float* b1 = (const float*)d_in[5];
  const float* W2 = (const float*)d_in[6];
  const float* b2 = (const float*)d_in[7];
  const float* W3 = (const float*)d_in[8];
  const float* b3 = (const float*)d_in[9];
  const float* W4 = (const float*)d_in[10];
  const float* b4 = (const float*)d_in[11];

  float* out0 = (float*)d_out;                         // (65536, 384)
  float* out1 = out0 + (size_t)65536 * 384;            // (1024, 384)

  char* ws = (char*)d_ws;
  unsigned short* meanb = (unsigned short*)(ws);            // 131072 bf16, 256 KiB
  unsigned short* W1f   = (unsigned short*)(ws + 262144);   // 98304 bf16, 192 KiB
  unsigned short* W2f   = (unsigned short*)(ws + 458752);   // 65536 bf16, 128 KiB
  unsigned short* W3f   = (unsigned short*)(ws + 589824);   // 65536 bf16, 128 KiB
  unsigned short* W4f   = (unsigned short*)(ws + 720896);   // 65536 bf16, 128 KiB

  hipLaunchKernelGGL(wprep, dim3(288), dim3(256), 0, stream,
                     W1, W2, W3, W4, W1f, W2f, W3f, W4f);
  hipLaunchKernelGGL(fusedU, dim3(1024), dim3(512), 0, stream,
                     user, ris, W1f, W2f, b1, b2, out0, meanb);
  hipLaunchKernelGGL(fusedR, dim3(16), dim3(512), 0, stream,
                     ris, meanb, W3f, W4f, b3, b4, out1);
}